// Round 2
// baseline (3667.257 us; speedup 1.0000x reference)
//
#include <hip/hip_runtime.h>
#include <math.h>

// ---------------- types ----------------
typedef _Float16 f16;
typedef _Float16 f16x8 __attribute__((ext_vector_type(8)));
typedef float f32x4 __attribute__((ext_vector_type(4)));

#define DEV static __device__ __forceinline__

DEV float sigm(float x)  { return 1.0f / (1.0f + __expf(-x)); }
DEV float tanhfast(float x) { return 2.0f / (1.0f + __expf(-2.0f * x)) - 1.0f; }

// async global->LDS, 16B per lane (dest must be wave-uniform base + lane*16)
DEV void gld16(const void* g, void* l) {
  __builtin_amdgcn_global_load_lds((const __attribute__((address_space(1))) void*)g,
                                   (__attribute__((address_space(3))) void*)l, 16, 0, 0);
}

// ---------------- problem constants ----------------
// B=256 V=50 N=32 D=128 H=384 L=12 CS=10 ND=4096 G=1560 OUT=128
#define GP 1664   // padded G (13*128) — XK gemm N and XK row stride
#define RK 416    // padded rec K (384 h + tv + tv_for_kwlast -> 416, mult of 32)
#define XOS 1560  // xo LDS row stride (exact G)
#define KH 3840   // H*CS (conv gemm K)
#define KO 19200  // V*H  (out gemm K)

// ---------------- workspace layout (bytes) ----------------
static constexpr size_t OFF_X     = 0;                       // 12800*4096*2 = 104857600
static constexpr size_t OFF_LH    = 0;                       // aliases x (dead after XK gemm)
static constexpr size_t OFF_OPART = 0;                       // aliases lh (dead after conv gemm)
static constexpr size_t OFF_WK    = 104857600;               // 1664*4096*2 = 13631488
static constexpr size_t OFF_XK    = OFF_WK + 13631488;       // 12800*1664*4 = 85196800
static constexpr size_t OFF_MLH   = OFF_XK;                  // aliases XK (dead after recurrence)
static constexpr size_t OFF_S1    = OFF_XK + 19660800;
static constexpr size_t OFF_TH    = OFF_S1 + 3276800;
static constexpr size_t OFF_CV    = OFF_TH + 19660800;       // ends < OFF_XK + 85196800
static constexpr size_t OFF_RW    = OFF_XK + 85196800;       // 1664*416*2 = 1384448
static constexpr size_t OFF_BIASC = OFF_RW + 1384448;        // 1664*4 -> pad 8192
static constexpr size_t OFF_HALL  = OFF_BIASC + 8192;        // 50*256*384*4 = 19660800
static constexpr size_t OFF_LD    = OFF_HALL + 19660800;     // 512000
static constexpr size_t OFF_WC2   = OFF_LD + 512000;         // 2949120
static constexpr size_t OFF_RNN   = OFF_WC2 + 2949120;       // 9830400
static constexpr size_t OFF_OUTW  = OFF_RNN + 9830400;       // 4915200

// ---------------- kernels ----------------

// embedding gather -> x_f16 (12800 x 4096), 8 halfs / thread
__global__ __launch_bounds__(256) void k_gather(const int* __restrict__ ids,
                                                const float* __restrict__ embed,
                                                f16* __restrict__ xf) {
  int i = blockIdx.x * 256 + threadIdx.x;     // 12800*512 total
  int row = i >> 9;
  int c8  = i & 511;
  int n = c8 >> 4;
  int d = (c8 & 15) << 3;
  int id = ids[row * 32 + n];
  const float* e = embed + (long)id * 128 + d;
  float4 a = *(const float4*)e;
  float4 b = *(const float4*)(e + 4);
  f16x8 o;
  o[0]=(f16)a.x; o[1]=(f16)a.y; o[2]=(f16)a.z; o[3]=(f16)a.w;
  o[4]=(f16)b.x; o[5]=(f16)b.y; o[6]=(f16)b.z; o[7]=(f16)b.w;
  *(f16x8*)(xf + ((long)row << 12) + (c8 << 3)) = o;
}

// kernel_w (1560 x 4097) -> Wk_f16 (1664 x 4096, zero-padded rows); biasc = kb+rb (padded 1664)
__global__ __launch_bounds__(256) void k_prep_wk(const float* __restrict__ kw,
                                                 const float* __restrict__ kb,
                                                 const float* __restrict__ rb,
                                                 f16* __restrict__ Wk,
                                                 float* __restrict__ biasc) {
  long i = (long)blockIdx.x * 256 + threadIdx.x;
  if (i < 1664L * 4096) {
    int nn = (int)(i >> 12);
    int k  = (int)(i & 4095);
    float v = (nn < 1560) ? kw[(long)nn * 4097 + k] : 0.0f;
    Wk[i] = (f16)v;
  }
  if (i < 1664) biasc[i] = (i < 1560) ? (kb[i] + rb[i]) : 0.0f;
}

// rec_w (1560 x 385) -> RW_f16 (1664 x 416): cols 0..384 = rec_w, col 385 = kernel_w[:,4096]
__global__ __launch_bounds__(256) void k_prep_rw(const float* __restrict__ rw,
                                                 const float* __restrict__ kw,
                                                 f16* __restrict__ RW) {
  long i = (long)blockIdx.x * 256 + threadIdx.x;
  if (i >= 1664L * 416) return;
  int nn = (int)(i / 416);
  int k  = (int)(i - (long)nn * 416);
  float v = 0.0f;
  if (nn < 1560) {
    if (k < 385) v = rw[(long)nn * 385 + k];
    else if (k == 385) v = kw[(long)nn * 4097 + 4096];
  }
  RW[i] = (f16)v;
}

// conv_w (384,384,10) -> Wc2_f16[o][j*384+h]
__global__ __launch_bounds__(256) void k_prep_wc(const float* __restrict__ cw,
                                                 f16* __restrict__ Wc2) {
  int i = blockIdx.x * 256 + threadIdx.x;     // 384*3840
  if (i >= 384 * 3840) return;
  int o = i / 3840;
  int c = i - o * 3840;
  int j = c / 384;
  int h = c - j * 384;
  Wc2[i] = (f16)cw[((long)o * 384 + h) * 10 + j];
}

// generic fp32 -> f16 convert
__global__ __launch_bounds__(256) void k_cvt(const float* __restrict__ src,
                                             f16* __restrict__ dst, long n) {
  long i = (long)blockIdx.x * 256 + threadIdx.x;
  if (i < n) dst[i] = (f16)src[i];
}

// C = A(M x K) * W(N x K)^T (+bias[col]); m97-style global_load_lds staging.
// grid.z splits K: block z handles k in [z*kLen, (z+1)*kLen), writes C + z*M*N.
__global__ __launch_bounds__(256) void k_gemm_bt(const f16* __restrict__ A,
                                                 const f16* __restrict__ W,
                                                 float* __restrict__ C,
                                                 const float* __restrict__ bias,
                                                 int N, int K, int kLen) {
  __shared__ __align__(16) f16 As[128 * 32];   // unpadded: global_load_lds needs lane-contiguous dest
  __shared__ __align__(16) f16 Bs[128 * 32];
  const int tid = threadIdx.x;
  const long rowA0 = (long)blockIdx.x * 128;
  const long rowB0 = (long)blockIdx.y * 128;
  const long ks = (long)blockIdx.z * kLen;
  C += (long)blockIdx.z * ((long)gridDim.x * 128 * N);
  const int w = tid >> 6, lane = tid & 63;
  const int q = lane >> 4, r16 = lane & 15;
  const int wr = w >> 1, wc = w & 1;
  f32x4 acc[4][4] = {};
  // staging map: thread t covers row t/4 (and +64), half-col (t%4)*8; LDS dest = base + t*16B
  const int srow = tid >> 2;
  const int scol = (tid & 3) * 8;
  const f16* gA0 = A + (rowA0 + srow) * (long)K + ks + scol;
  const f16* gA1 = gA0 + 64L * K;
  const f16* gB0 = W + (rowB0 + srow) * (long)K + ks + scol;
  const f16* gB1 = gB0 + 64L * K;
  f16* lA = As + tid * 8;
  f16* lB = Bs + tid * 8;
  for (int k0 = 0; k0 < kLen; k0 += 32) {
    __syncthreads();                      // prior ds_reads done before overwrite
    gld16(gA0 + k0, lA);
    gld16(gA1 + k0, lA + 2048);
    gld16(gB0 + k0, lB);
    gld16(gB1 + k0, lB + 2048);
    __syncthreads();                      // vmcnt(0) drained by barrier
    f16x8 af[4], bfr[4];
#pragma unroll
    for (int i = 0; i < 4; i++) {
      af[i]  = *(const f16x8*)&As[(wr * 64 + i * 16 + r16) * 32 + q * 8];
      bfr[i] = *(const f16x8*)&Bs[(wc * 64 + i * 16 + r16) * 32 + q * 8];
    }
#pragma unroll
    for (int i = 0; i < 4; i++)
#pragma unroll
      for (int j = 0; j < 4; j++)
        acc[i][j] = __builtin_amdgcn_mfma_f32_16x16x32_f16(af[i], bfr[j], acc[i][j], 0, 0, 0);
  }
  // C[row=q*4+r][col=lane&15] per 16x16 tile
#pragma unroll
  for (int i = 0; i < 4; i++)
#pragma unroll
    for (int j = 0; j < 4; j++) {
      long row = rowA0 + wr * 64 + i * 16 + q * 4;
      long col = rowB0 + wc * 64 + j * 16 + r16;
      float bv = bias ? bias[col] : 0.0f;
#pragma unroll
      for (int r = 0; r < 4; r++)
        C[(row + r) * (long)N + col] = acc[i][j][r] + bv;
    }
}

// sequential scan: 32 blocks x 8 batches x 512 threads (8 waves, 2/SIMD).
// xo = XK(bias-folded) + h_ext @ RW^T where h_ext = [h, tv, tv] (tv*kw_last folded into RW col 385).
__global__ __launch_bounds__(512, 2) void k_recur(const float* __restrict__ XK,   // (12800, 1664) pre-biased
                                                  const f16* __restrict__ RW,     // (1664, 416)
                                                  const float* __restrict__ timep,// (256,50)
                                                  float* __restrict__ h_all,      // (50,256,384)
                                                  float* __restrict__ dists) {    // (50,256)
  __shared__ float xo[8 * XOS];                 // 49920 B
  __shared__ __align__(16) f16 hext[16 * 424];  // 13568 B
  const int tid = threadIdx.x;
  const int b0 = blockIdx.x * 8;
  for (int i = tid; i < 16 * 424; i += 512) hext[i] = (f16)0.0f;
  __syncthreads();
  if (tid < 8) {
    float tv = timep[(b0 + tid) * 50];
    hext[tid * 424 + 384] = (f16)tv;
    hext[tid * 424 + 385] = (f16)tv;
  }
  const int lane = tid & 63, w = tid >> 6;
  const int q = lane >> 4, r16 = lane & 15;
  // gate mapping: thread = (batch gm, l-half ghalf, channel gch)
  const int gm = tid >> 6;
  const int ghalf = (tid >> 5) & 1;
  const int gch = tid & 31;
  const int gl0 = ghalf * 6;
  float creg[6] = {0, 0, 0, 0, 0, 0};

  for (int t = 0; t < 50; t++) {
    // (A) XK gate prefetch — no in-step deps, hides L3 latency under MFMA phase
    const float* xkrow = XK + ((long)(b0 + gm) * 50 + t) * GP;
    float xkg[4][6];
#pragma unroll
    for (int g = 0; g < 4; g++)
#pragma unroll
      for (int j = 0; j < 6; j++)
        xkg[g][j] = xkrow[24 + (g * 12 + gl0 + j) * 32 + gch];

    __syncthreads();   // (B) hext ready
    // (C) rec GEMM: wave w owns cols [w*208, w*208+208), 13 tiles of 16, 2-deep W pipeline
    f16x8 af[13];
    const f16* hrow = hext + r16 * 424 + q * 8;
#pragma unroll
    for (int kt = 0; kt < 13; kt++) af[kt] = *(const f16x8*)(hrow + kt * 32);
    const int nbase = w * 208;
    f16x8 W0[13], W1[13];
    {
      const f16* wr0 = RW + (long)(nbase + r16) * RK + q * 8;
#pragma unroll
      for (int kt = 0; kt < 13; kt++) W0[kt] = *(const f16x8*)(wr0 + kt * 32);
    }
    for (int nt = 0; nt < 13; nt++) {
      if (nt < 12) {
        const f16* wr1 = RW + (long)(nbase + (nt + 1) * 16 + r16) * RK + q * 8;
#pragma unroll
        for (int kt = 0; kt < 13; kt++) W1[kt] = *(const f16x8*)(wr1 + kt * 32);
      }
      f32x4 a0 = {};
#pragma unroll
      for (int kt = 0; kt < 13; kt++)
        a0 = __builtin_amdgcn_mfma_f32_16x16x32_f16(af[kt], W0[kt], a0, 0, 0, 0);
      int n0 = nbase + nt * 16;
#pragma unroll
      for (int r = 0; r < 4; r++) {
        int rr = q * 4 + r;
        if (rr < 8 && n0 + r16 < XOS) xo[rr * XOS + n0 + r16] = a0[r];
      }
#pragma unroll
      for (int kt = 0; kt < 13; kt++) W0[kt] = W1[kt];
    }
    __syncthreads();   // (D) xo ready
    // (E) gates
    {
      const float* xom = xo + gm * XOS;
      int b = b0 + gm;
      float fm[12], im[12];
      {
        float v1[12], v2[12];
        float mx1 = -1e30f, mx2 = -1e30f;
#pragma unroll
        for (int l = 0; l < 12; l++) {
          v1[l] = xom[l] + xkrow[l];
          v2[l] = xom[12 + l] + xkrow[12 + l];
          mx1 = fmaxf(mx1, v1[l]); mx2 = fmaxf(mx2, v2[l]);
        }
        float s1 = 0.0f, s2 = 0.0f;
#pragma unroll
        for (int l = 0; l < 12; l++) {
          v1[l] = __expf(v1[l] - mx1); s1 += v1[l];
          v2[l] = __expf(v2[l] - mx2); s2 += v2[l];
        }
        float i1 = 1.0f / s1, i2 = 1.0f / s2, c1 = 0.0f, c2 = 0.0f;
#pragma unroll
        for (int l = 0; l < 12; l++) { c1 += v1[l]; fm[l] = c1 * i1; }
#pragma unroll
        for (int l = 11; l >= 0; l--) { c2 += v2[l]; im[l] = c2 * i2; }
      }
      if (ghalf == 0 && gch == 0) {
        float ds = 0.0f;
#pragma unroll
        for (int l = 0; l < 12; l++) ds += fm[l];
        dists[t * 256 + b] = 1.0f - ds * (1.0f / 12.0f);
      }
      float* hdst = h_all + ((long)t * 256 + b) * 384;
#pragma unroll
      for (int j = 0; j < 6; j++) {
        int l = gl0 + j;
        float fv = sigm(xom[24 + l * 32 + gch]         + xkg[0][j]);
        float iv = sigm(xom[24 + (12 + l) * 32 + gch]  + xkg[1][j]);
        float og = sigm(xom[24 + (24 + l) * 32 + gch]  + xkg[2][j]);
        float ci = tanhfast(xom[24 + (36 + l) * 32 + gch] + xkg[3][j]);
        float fmv = fm[l], imv = im[l], ov = fmv * imv;
        float cn = ov * (fv * creg[j] + iv * ci) + (fmv - ov) * creg[j] + (imv - ov) * ci;
        creg[j] = cn;
        float hv = og * tanhfast(cn);
        hdst[l * 32 + gch] = hv;
        hext[gm * 424 + l * 32 + gch] = (f16)hv;
      }
      if (ghalf == 1 && gch == 0 && t < 49) {
        float tv = timep[b * 50 + t + 1];
        hext[gm * 424 + 384] = (f16)tv;
        hext[gm * 424 + 385] = (f16)tv;
      }
    }
  }
}

// ld[b,t,:] = softmax_j(cumsum_j dist[t-9+j])
__global__ __launch_bounds__(256) void k_ld(const float* __restrict__ dists,
                                            float* __restrict__ ld) {
  int i = blockIdx.x * 256 + threadIdx.x;
  if (i >= 12800) return;
  int b = i / 50, t = i - b * 50;
  float v[10];
  float cum = 0.0f, mx = -1e30f;
#pragma unroll
  for (int j = 0; j < 10; j++) {
    int s = t - 9 + j;
    float d = (s >= 0) ? dists[s * 256 + b] : 0.0f;
    cum += d; v[j] = cum; mx = fmaxf(mx, cum);
  }
  float sum = 0.0f;
#pragma unroll
  for (int j = 0; j < 10; j++) { v[j] = __expf(v[j] - mx); sum += v[j]; }
  float inv = 1.0f / sum;
#pragma unroll
  for (int j = 0; j < 10; j++) ld[i * 10 + j] = v[j] * inv;
}

// lh_f16[(b,t)][j*384+h] = ld[b,t,j] * h_{t-9+j}[b,h]
__global__ __launch_bounds__(256) void k_lh(const float* __restrict__ ld,
                                            const float* __restrict__ h_all,
                                            f16* __restrict__ lh) {
  int i = blockIdx.x * 256 + threadIdx.x;   // 12800*480
  int row = i / 480;
  int c = i - row * 480;
  int j = c / 48;
  int h0 = (c - j * 48) * 8;
  int b = row / 50, t = row - b * 50;
  int s = t - 9 + j;
  f16x8 o;
  if (s >= 0) {
    float wv = ld[row * 10 + j];
    const float* hp = h_all + ((long)s * 256 + b) * 384 + h0;
#pragma unroll
    for (int k = 0; k < 8; k++) o[k] = (f16)(wv * hp[k]);
  } else {
#pragma unroll
    for (int k = 0; k < 8; k++) o[k] = (f16)0.0f;
  }
  *(f16x8*)(lh + (long)row * KH + j * 384 + h0) = o;
}

// mlh[(b,t)][h] = mean_j lh
__global__ __launch_bounds__(256) void k_mlh(const float* __restrict__ ld,
                                             const float* __restrict__ h_all,
                                             float* __restrict__ mlh) {
  int i = blockIdx.x * 256 + threadIdx.x;   // 12800*384
  int row = i / 384, h = i - row * 384;
  int b = row / 50, t = row - b * 50;
  float acc = 0.0f;
#pragma unroll
  for (int j = 0; j < 10; j++) {
    int s = t - 9 + j;
    if (s >= 0) acc += ld[row * 10 + j] * h_all[((long)s * 256 + b) * 384 + h];
  }
  mlh[i] = acc * 0.1f;
}

// s1 = relu(mlh @ scale_w^T + scale_b), (12800 x 64)
__global__ __launch_bounds__(256) void k_scale1(const float* __restrict__ mlh,
                                                const float* __restrict__ sw,
                                                const float* __restrict__ sb,
                                                float* __restrict__ s1) {
  int i = blockIdx.x * 256 + threadIdx.x;   // 12800*64
  int row = i >> 6, o = i & 63;
  const float* a = mlh + (long)row * 384;
  const float* wv = sw + o * 384;
  float acc = 0.0f;
  for (int k = 0; k < 384; k += 4)
    acc += a[k] * wv[k] + a[k + 1] * wv[k + 1] + a[k + 2] * wv[k + 2] + a[k + 3] * wv[k + 3];
  s1[i] = fmaxf(acc + sb[o], 0.0f);
}

// theme = sigmoid(s1 @ rescale_w^T + rescale_b), (12800 x 384)
__global__ __launch_bounds__(256) void k_scale2(const float* __restrict__ s1,
                                                const float* __restrict__ rw,
                                                const float* __restrict__ rb,
                                                float* __restrict__ theme) {
  int i = blockIdx.x * 256 + threadIdx.x;   // 12800*384
  int row = i / 384, o = i - row * 384;
  const float* a = s1 + (long)row * 64;
  const float* wv = rw + o * 64;
  float acc = 0.0f;
  for (int k = 0; k < 64; k += 4)
    acc += a[k] * wv[k] + a[k + 1] * wv[k + 1] + a[k + 2] * wv[k + 2] + a[k + 3] * wv[k + 3];
  theme[i] = sigm(acc + rb[o]);
}

// rnn_f16[b][t*384+h] = theme*conv + h
__global__ __launch_bounds__(256) void k_rnn(const float* __restrict__ theme,
                                             const float* __restrict__ conv,
                                             const float* __restrict__ h_all,
                                             f16* __restrict__ rnn) {
  int i = blockIdx.x * 256 + threadIdx.x;   // 12800*384, ordered (b,t,h)
  int row = i / 384, h = i - row * 384;
  int b = row / 50, t = row - b * 50;
  float local = theme[i] * conv[i];
  float hv = h_all[((long)t * 256 + b) * 384 + h];
  rnn[i] = (f16)(local + hv);               // (b*50+t)*384+h == b*19200 + t*384 + h
}

// out[i] = sum_z part[z][i] + out_b
__global__ __launch_bounds__(256) void k_red8(const float* __restrict__ part,
                                              const float* __restrict__ ob,
                                              float* __restrict__ out) {
  int i = blockIdx.x * 256 + threadIdx.x;   // 32768
  float s = 0.0f;
#pragma unroll
  for (int z = 0; z < 8; z++) s += part[z * 32768 + i];
  out[i] = s + ob[i & 127];
}

// ---------------- launch ----------------
extern "C" void kernel_launch(void* const* d_in, const int* in_sizes, int n_in,
                              void* d_out, int out_size, void* d_ws, size_t ws_size,
                              hipStream_t stream) {
  (void)in_sizes; (void)n_in; (void)out_size; (void)ws_size;
  const int*   node_ids  = (const int*)  d_in[0];
  const float* timep     = (const float*)d_in[3];
  const float* embed     = (const float*)d_in[6];
  const float* kernel_w  = (const float*)d_in[7];
  const float* kernel_b  = (const float*)d_in[8];
  const float* rec_w     = (const float*)d_in[9];
  const float* rec_b     = (const float*)d_in[10];
  const float* scale_w   = (const float*)d_in[11];
  const float* scale_b   = (const float*)d_in[12];
  const float* rescale_w = (const float*)d_in[13];
  const float* rescale_b = (const float*)d_in[14];
  const float* conv_w    = (const float*)d_in[15];
  const float* conv_b    = (const float*)d_in[16];
  const float* out_w     = (const float*)d_in[17];
  const float* out_b     = (const float*)d_in[18];

  char* ws = (char*)d_ws;
  f16*   xf      = (f16*)  (ws + OFF_X);
  f16*   lh      = (f16*)  (ws + OFF_LH);
  float* opart   = (float*)(ws + OFF_OPART);
  f16*   Wk      = (f16*)  (ws + OFF_WK);
  float* XK      = (float*)(ws + OFF_XK);
  float* mlh     = (float*)(ws + OFF_MLH);
  float* s1      = (float*)(ws + OFF_S1);
  float* theme   = (float*)(ws + OFF_TH);
  float* convbuf = (float*)(ws + OFF_CV);
  f16*   RW      = (f16*)  (ws + OFF_RW);
  float* biasc   = (float*)(ws + OFF_BIASC);
  float* h_all   = (float*)(ws + OFF_HALL);
  float* ldbuf   = (float*)(ws + OFF_LD);
  f16*   Wc2     = (f16*)  (ws + OFF_WC2);
  f16*   rnn     = (f16*)  (ws + OFF_RNN);
  f16*   outw    = (f16*)  (ws + OFF_OUTW);

  float* outp  = (float*)d_out;          // (256,128)
  float* dists = outp + 256 * 128;       // (50,256)

  // phase 0: prep
  k_gather <<<25600, 256, 0, stream>>>(node_ids, embed, xf);
  k_prep_wk<<<26624, 256, 0, stream>>>(kernel_w, kernel_b, rec_b, Wk, biasc);
  k_prep_rw<<<2704,  256, 0, stream>>>(rec_w, kernel_w, RW);
  // phase 1: XK = x @ kernel_w^T + (kernel_b + rec_b)   (hoisted out of the scan)
  k_gemm_bt<<<dim3(100, 13), 256, 0, stream>>>(xf, Wk, XK, biasc, GP, 4096, 4096);
  // phase 2: sequential recurrence (per-batch independent)
  k_recur<<<32, 512, 0, stream>>>(XK, RW, timep, h_all, dists);
  // phase 3: deferred outputs (fully parallel)
  k_ld  <<<50,    256, 0, stream>>>(dists, ldbuf);
  k_lh  <<<24000, 256, 0, stream>>>(ldbuf, h_all, lh);
  k_mlh <<<19200, 256, 0, stream>>>(ldbuf, h_all, mlh);
  k_scale1<<<3200,  256, 0, stream>>>(mlh, scale_w, scale_b, s1);
  k_scale2<<<19200, 256, 0, stream>>>(s1, rescale_w, rescale_b, theme);
  k_prep_wc<<<5760, 256, 0, stream>>>(conv_w, Wc2);
  k_gemm_bt<<<dim3(100, 3), 256, 0, stream>>>(lh, Wc2, convbuf, conv_b, 384, KH, KH);
  k_rnn <<<19200, 256, 0, stream>>>(theme, convbuf, h_all, rnn);
  k_cvt <<<9600,  256, 0, stream>>>(out_w, outw, 128L * KO);
  // phase 4: out = rnn @ out_w^T + out_b   (K split 8 ways, then reduce)
  k_gemm_bt<<<dim3(2, 1, 8), 256, 0, stream>>>(rnn, outw, opart, nullptr, 128, KO, KO / 8);
  k_red8<<<128, 256, 0, stream>>>(opart, out_b, outp);
}

// Round 3
// 2178.456 us; speedup vs baseline: 1.6834x; 1.6834x over previous
//
#include <hip/hip_runtime.h>
#include <math.h>

// ---------------- types ----------------
typedef _Float16 f16;
typedef _Float16 f16x8 __attribute__((ext_vector_type(8)));
typedef float f32x4 __attribute__((ext_vector_type(4)));

#define DEV static __device__ __forceinline__

DEV float sigm(float x)  { return 1.0f / (1.0f + __expf(-x)); }
DEV float tanhfast(float x) { return 2.0f / (1.0f + __expf(-2.0f * x)) - 1.0f; }

// async global->LDS, 16B per lane (dest must be wave-uniform base + lane*16)
DEV void gld16(const void* g, void* l) {
  __builtin_amdgcn_global_load_lds((const __attribute__((address_space(1))) void*)g,
                                   (__attribute__((address_space(3))) void*)l, 16, 0, 0);
}

// ---------------- problem constants ----------------
// B=256 V=50 N=32 D=128 H=384 L=12 CS=10 ND=4096 G=1560 OUT=128
#define GP 1664   // padded G (13*128) — XK gemm N and XKh row stride
#define RK 416    // padded rec K (384 h + tv + tv_kwlast -> 416, mult of 32)
#define XOS 1572  // xo LDS row stride in f16 (1568 cols + 4 pad -> conflict-free stores)
#define KH 3840   // H*CS (conv gemm K)
#define KO 19200  // V*H  (out gemm K)

// ---------------- workspace layout (bytes) ----------------
static constexpr size_t OFF_X     = 0;                       // xf 104857600; lh aliases; opart aliases
static constexpr size_t OFF_LH    = 0;
static constexpr size_t OFF_OPART = 0;
static constexpr size_t OFF_WK    = 104857600;               // 13631488
static constexpr size_t OFF_XK    = OFF_WK + 13631488;       // XKh f16 12800*1664*2 = 42598400
// aliases of the XK region (XKh dead after k_recur; swp/rwp2/sbp live beyond 42.6MB mark):
static constexpr size_t OFF_MLH   = OFF_XK;                  // mlh_h f16 9830400
static constexpr size_t OFF_S1    = OFF_XK + 9830400;        // s1h f16 3276800
static constexpr size_t OFF_TH    = OFF_XK + 13107200;       // theme f32 19660800
static constexpr size_t OFF_CV    = OFF_XK + 32768000;       // conv f32 19660800 (ends +52428800)
static constexpr size_t OFF_SWP   = OFF_XK + 52428800;       // swp f16 98304 (written phase 0, > XKh end)
static constexpr size_t OFF_RWP2  = OFF_XK + 52527104;       // rwp2 f16 98304
static constexpr size_t OFF_SBP   = OFF_XK + 52625408;       // sbp f32 512
static constexpr size_t OFF_RW    = OFF_XK + 85196800;       // RW f16 1664*416*2 = 1384448
static constexpr size_t OFF_BIASC = OFF_RW + 1384448;        // 8192
static constexpr size_t OFF_HALL  = OFF_BIASC + 8192;        // h_all f32 19660800
static constexpr size_t OFF_LD    = OFF_HALL + 19660800;     // 512000
static constexpr size_t OFF_WC2   = OFF_LD + 512000;         // 2949120
static constexpr size_t OFF_RNN   = OFF_WC2 + 2949120;       // 9830400
static constexpr size_t OFF_OUTW  = OFF_RNN + 9830400;       // 4915200

// ---------------- kernels ----------------

// embedding gather -> x_f16 (12800 x 4096), 8 halfs / thread
__global__ __launch_bounds__(256) void k_gather(const int* __restrict__ ids,
                                                const float* __restrict__ embed,
                                                f16* __restrict__ xf) {
  int i = blockIdx.x * 256 + threadIdx.x;     // 12800*512 total
  int row = i >> 9;
  int c8  = i & 511;
  int n = c8 >> 4;
  int d = (c8 & 15) << 3;
  int id = ids[row * 32 + n];
  const float* e = embed + (long)id * 128 + d;
  float4 a = *(const float4*)e;
  float4 b = *(const float4*)(e + 4);
  f16x8 o;
  o[0]=(f16)a.x; o[1]=(f16)a.y; o[2]=(f16)a.z; o[3]=(f16)a.w;
  o[4]=(f16)b.x; o[5]=(f16)b.y; o[6]=(f16)b.z; o[7]=(f16)b.w;
  *(f16x8*)(xf + ((long)row << 12) + (c8 << 3)) = o;
}

// kernel_w (1560 x 4097) -> Wk_f16 (1664 x 4096, zero-padded rows); biasc = kb+rb (padded 1664)
__global__ __launch_bounds__(256) void k_prep_wk(const float* __restrict__ kw,
                                                 const float* __restrict__ kb,
                                                 const float* __restrict__ rb,
                                                 f16* __restrict__ Wk,
                                                 float* __restrict__ biasc) {
  long i = (long)blockIdx.x * 256 + threadIdx.x;
  if (i < 1664L * 4096) {
    int nn = (int)(i >> 12);
    int k  = (int)(i & 4095);
    float v = (nn < 1560) ? kw[(long)nn * 4097 + k] : 0.0f;
    Wk[i] = (f16)v;
  }
  if (i < 1664) biasc[i] = (i < 1560) ? (kb[i] + rb[i]) : 0.0f;
}

// rec_w (1560 x 385) -> RW_f16 (1664 x 416): cols 0..384 = rec_w, col 385 = kernel_w[:,4096]
__global__ __launch_bounds__(256) void k_prep_rw(const float* __restrict__ rw,
                                                 const float* __restrict__ kw,
                                                 f16* __restrict__ RW) {
  long i = (long)blockIdx.x * 256 + threadIdx.x;
  if (i >= 1664L * 416) return;
  int nn = (int)(i / 416);
  int k  = (int)(i - (long)nn * 416);
  float v = 0.0f;
  if (nn < 1560) {
    if (k < 385) v = rw[(long)nn * 385 + k];
    else if (k == 385) v = kw[(long)nn * 4097 + 4096];
  }
  RW[i] = (f16)v;
}

// conv_w (384,384,10) -> Wc2_f16[o][j*384+h]
__global__ __launch_bounds__(256) void k_prep_wc(const float* __restrict__ cw,
                                                 f16* __restrict__ Wc2) {
  int i = blockIdx.x * 256 + threadIdx.x;     // 384*3840
  if (i >= 384 * 3840) return;
  int o = i / 3840;
  int c = i - o * 3840;
  int j = c / 384;
  int h = c - j * 384;
  Wc2[i] = (f16)cw[((long)o * 384 + h) * 10 + j];
}

// scale_w (64,384)->swp(128,384,f16,zero-pad rows); scale_b->sbp(128); rescale_w(384,64)->rwp2(384,128,zero-pad cols)
__global__ __launch_bounds__(256) void k_prep_scale(const float* __restrict__ sw,
                                                    const float* __restrict__ sb,
                                                    const float* __restrict__ rw2,
                                                    f16* __restrict__ swp,
                                                    float* __restrict__ sbp,
                                                    f16* __restrict__ rwp2) {
  int i = blockIdx.x * 256 + threadIdx.x;   // 49152
  if (i < 128 * 384) {
    int o = i / 384, k = i - o * 384;
    swp[i] = (f16)((o < 64) ? sw[o * 384 + k] : 0.0f);
    int o2 = i >> 7, k2 = i & 127;
    rwp2[i] = (f16)((k2 < 64) ? rw2[o2 * 64 + k2] : 0.0f);
  }
  if (i < 128) sbp[i] = (i < 64) ? sb[i] : 0.0f;
}

// generic fp32 -> f16 convert
__global__ __launch_bounds__(256) void k_cvt(const float* __restrict__ src,
                                             f16* __restrict__ dst, long n) {
  long i = (long)blockIdx.x * 256 + threadIdx.x;
  if (i < n) dst[i] = (f16)src[i];
}

// C = A(M x K) * W(N x K)^T (+bias[col]); m97-style global_load_lds staging.
// grid.z splits K (writes partials at z*M*N). act: 0=f32, 1=f16, 2=relu->f16, 3=sigmoid->f32.
__global__ __launch_bounds__(256) void k_gemm_bt(const f16* __restrict__ A,
                                                 const f16* __restrict__ W,
                                                 void* __restrict__ Cv,
                                                 const float* __restrict__ bias,
                                                 int N, int K, int kLen, int act) {
  __shared__ __align__(16) f16 As[128 * 32];   // unpadded: global_load_lds needs lane-contiguous dest
  __shared__ __align__(16) f16 Bs[128 * 32];
  const int tid = threadIdx.x;
  const long rowA0 = (long)blockIdx.x * 128;
  const long rowB0 = (long)blockIdx.y * 128;
  const long ks = (long)blockIdx.z * kLen;
  const long zoff = (long)blockIdx.z * ((long)gridDim.x * 128 * N);
  const int w = tid >> 6, lane = tid & 63;
  const int q = lane >> 4, r16 = lane & 15;
  const int wr = w >> 1, wc = w & 1;
  f32x4 acc[4][4] = {};
  const int srow = tid >> 2;
  const int scol = (tid & 3) * 8;
  const f16* gA0 = A + (rowA0 + srow) * (long)K + ks + scol;
  const f16* gA1 = gA0 + 64L * K;
  const f16* gB0 = W + (rowB0 + srow) * (long)K + ks + scol;
  const f16* gB1 = gB0 + 64L * K;
  f16* lA = As + tid * 8;
  f16* lB = Bs + tid * 8;
  for (int k0 = 0; k0 < kLen; k0 += 32) {
    __syncthreads();
    gld16(gA0 + k0, lA);
    gld16(gA1 + k0, lA + 2048);
    gld16(gB0 + k0, lB);
    gld16(gB1 + k0, lB + 2048);
    __syncthreads();
    f16x8 af[4], bfr[4];
#pragma unroll
    for (int i = 0; i < 4; i++) {
      af[i]  = *(const f16x8*)&As[(wr * 64 + i * 16 + r16) * 32 + q * 8];
      bfr[i] = *(const f16x8*)&Bs[(wc * 64 + i * 16 + r16) * 32 + q * 8];
    }
#pragma unroll
    for (int i = 0; i < 4; i++)
#pragma unroll
      for (int j = 0; j < 4; j++)
        acc[i][j] = __builtin_amdgcn_mfma_f32_16x16x32_f16(af[i], bfr[j], acc[i][j], 0, 0, 0);
  }
#pragma unroll
  for (int i = 0; i < 4; i++)
#pragma unroll
    for (int j = 0; j < 4; j++) {
      long row = rowA0 + wr * 64 + i * 16 + q * 4;
      long col = rowB0 + wc * 64 + j * 16 + r16;
      float bv = bias ? bias[col] : 0.0f;
#pragma unroll
      for (int r = 0; r < 4; r++) {
        float v = acc[i][j][r] + bv;
        long off = (row + r) * (long)N + col + zoff;
        if (act == 0)      ((float*)Cv)[off] = v;
        else if (act == 1) ((f16*)Cv)[off]   = (f16)v;
        else if (act == 2) ((f16*)Cv)[off]   = (f16)fmaxf(v, 0.0f);
        else               ((float*)Cv)[off] = sigm(v);
      }
    }
}

// sequential scan: 16 blocks x 16 batches x 512 threads; RW stays L2-resident (2 blocks/XCD).
// xo = XKh (acc-init, bias folded) + h_ext @ RW^T; h_ext = [h, tv, tv] (tv*kw_last in RW col 385).
__global__ __launch_bounds__(512, 1) void k_recur(const f16* __restrict__ XKh,  // (12800,1664) f16
                                                  const f16* __restrict__ RW,   // (1664,416) f16
                                                  const float* __restrict__ timep,
                                                  float* __restrict__ h_all,    // (50,256,384)
                                                  float* __restrict__ dists) {  // (50,256)
  __shared__ f16 xo[16 * XOS];                  // 50304 B
  __shared__ __align__(16) f16 hext[16 * 424];  // 13568 B  (total 63872 <= 64K)
  const int tid = threadIdx.x;
  const int b0 = blockIdx.x * 16;
  for (int i = tid; i < 16 * 424; i += 512) hext[i] = (f16)0;
  __syncthreads();
  if (tid < 16) {
    float tv = timep[(b0 + tid) * 50];
    hext[tid * 424 + 384] = (f16)tv;
    hext[tid * 424 + 385] = (f16)tv;
  }
  const int lane = tid & 63, w = tid >> 6;
  const int q = lane >> 4, r16 = lane & 15;
  const int gm = tid >> 5, gch = tid & 31;   // gate mapping: (batch, channel)
  float creg[12] = {};

  for (int t = 0; t < 50; t++) {
    __syncthreads();   // hext ready; xo/creg consumers of step t-1 done
    // A-fragments (hext rows = the 16 real batches)
    f16x8 af[13];
    const f16* hrow = hext + r16 * 424 + q * 8;
#pragma unroll
    for (int kt = 0; kt < 13; kt++) af[kt] = *(const f16x8*)(hrow + kt * 32);
    // XK acc-init gather base: row (b0 + q*4 + r), col (n0 + r16)
    const f16* xkbase = XKh + ((long)(b0 + q * 4) * 50 + t) * GP + r16;
    // wave w owns n-tiles {w, w+8, ...} <= 97; W + xk double-buffered one tile ahead
    int nt = w;
    f16x8 W0[13], W1[13];
    f16 xf0[4], xf1[4];
    {
      const f16* wr0 = RW + (long)(nt * 16 + r16) * RK + q * 8;
#pragma unroll
      for (int kt = 0; kt < 13; kt++) W0[kt] = *(const f16x8*)(wr0 + kt * 32);
#pragma unroll
      for (int r = 0; r < 4; r++) xf0[r] = xkbase[(long)r * 50 * GP + nt * 16];
    }
    while (nt <= 97) {
      const int ntn = nt + 8;
      if (ntn <= 97) {
        const f16* wr1 = RW + (long)(ntn * 16 + r16) * RK + q * 8;
#pragma unroll
        for (int kt = 0; kt < 13; kt++) W1[kt] = *(const f16x8*)(wr1 + kt * 32);
#pragma unroll
        for (int r = 0; r < 4; r++) xf1[r] = xkbase[(long)r * 50 * GP + ntn * 16];
      }
      f32x4 a0;
#pragma unroll
      for (int r = 0; r < 4; r++) a0[r] = (float)xf0[r];
#pragma unroll
      for (int kt = 0; kt < 13; kt++)
        a0 = __builtin_amdgcn_mfma_f32_16x16x32_f16(af[kt], W0[kt], a0, 0, 0, 0);
      const int c0 = nt * 16 + r16;
#pragma unroll
      for (int r = 0; r < 4; r++) xo[(q * 4 + r) * XOS + c0] = (f16)a0[r];
#pragma unroll
      for (int kt = 0; kt < 13; kt++) W0[kt] = W1[kt];
#pragma unroll
      for (int r = 0; r < 4; r++) xf0[r] = xf1[r];
      nt = ntn;
    }
    __syncthreads();   // xo ready
    // gates: thread = (batch gm, channel gch), all 12 l
    {
      const f16* xom = xo + gm * XOS;
      const int b = b0 + gm;
      float fm[12], im[12];
      {
        float v1[12], v2[12], mx1 = -1e30f, mx2 = -1e30f;
#pragma unroll
        for (int l = 0; l < 12; l++) {
          v1[l] = (float)xom[l];      mx1 = fmaxf(mx1, v1[l]);
          v2[l] = (float)xom[12 + l]; mx2 = fmaxf(mx2, v2[l]);
        }
        float s1 = 0.0f, s2 = 0.0f;
#pragma unroll
        for (int l = 0; l < 12; l++) {
          v1[l] = __expf(v1[l] - mx1); s1 += v1[l];
          v2[l] = __expf(v2[l] - mx2); s2 += v2[l];
        }
        float i1 = 1.0f / s1, i2 = 1.0f / s2, c1 = 0.0f, c2 = 0.0f;
#pragma unroll
        for (int l = 0; l < 12; l++) { c1 += v1[l]; fm[l] = c1 * i1; }
#pragma unroll
        for (int l = 11; l >= 0; l--) { c2 += v2[l]; im[l] = c2 * i2; }
      }
      if (gch == 0) {
        float ds = 0.0f;
#pragma unroll
        for (int l = 0; l < 12; l++) ds += fm[l];
        dists[t * 256 + b] = 1.0f - ds * (1.0f / 12.0f);
      }
      float* hdst = h_all + ((long)t * 256 + b) * 384;
#pragma unroll
      for (int l = 0; l < 12; l++) {
        float fv = sigm((float)xom[24 + l * 32 + gch]);
        float iv = sigm((float)xom[24 + (12 + l) * 32 + gch]);
        float og = sigm((float)xom[24 + (24 + l) * 32 + gch]);
        float ci = tanhfast((float)xom[24 + (36 + l) * 32 + gch]);
        float fmv = fm[l], imv = im[l], ov = fmv * imv;
        float cn = ov * (fv * creg[l] + iv * ci) + (fmv - ov) * creg[l] + (imv - ov) * ci;
        creg[l] = cn;
        float hv = og * tanhfast(cn);
        hdst[l * 32 + gch] = hv;
        hext[gm * 424 + l * 32 + gch] = (f16)hv;
      }
      if (gch == 1 && t < 49) {
        float tv = timep[b * 50 + t + 1];
        hext[gm * 424 + 384] = (f16)tv;
        hext[gm * 424 + 385] = (f16)tv;
      }
    }
  }
}

// ld[b,t,:] = softmax_j(cumsum_j dist[t-9+j])
__global__ __launch_bounds__(256) void k_ld(const float* __restrict__ dists,
                                            float* __restrict__ ld) {
  int i = blockIdx.x * 256 + threadIdx.x;
  if (i >= 12800) return;
  int b = i / 50, t = i - b * 50;
  float v[10];
  float cum = 0.0f, mx = -1e30f;
#pragma unroll
  for (int j = 0; j < 10; j++) {
    int s = t - 9 + j;
    float d = (s >= 0) ? dists[s * 256 + b] : 0.0f;
    cum += d; v[j] = cum; mx = fmaxf(mx, cum);
  }
  float sum = 0.0f;
#pragma unroll
  for (int j = 0; j < 10; j++) { v[j] = __expf(v[j] - mx); sum += v[j]; }
  float inv = 1.0f / sum;
#pragma unroll
  for (int j = 0; j < 10; j++) ld[i * 10 + j] = v[j] * inv;
}

// lh_f16[(b,t)][j*384+h] = ld[b,t,j] * h_{t-9+j}[b,h]
__global__ __launch_bounds__(256) void k_lh(const float* __restrict__ ld,
                                            const float* __restrict__ h_all,
                                            f16* __restrict__ lh) {
  int i = blockIdx.x * 256 + threadIdx.x;   // 12800*480
  int row = i / 480;
  int c = i - row * 480;
  int j = c / 48;
  int h0 = (c - j * 48) * 8;
  int b = row / 50, t = row - b * 50;
  int s = t - 9 + j;
  f16x8 o;
  if (s >= 0) {
    float wv = ld[row * 10 + j];
    const float* hp = h_all + ((long)s * 256 + b) * 384 + h0;
#pragma unroll
    for (int k = 0; k < 8; k++) o[k] = (f16)(wv * hp[k]);
  } else {
#pragma unroll
    for (int k = 0; k < 8; k++) o[k] = (f16)0.0f;
  }
  *(f16x8*)(lh + (long)row * KH + j * 384 + h0) = o;
}

// mlh_h[(b,t)][h] = mean_j (f16)
__global__ __launch_bounds__(256) void k_mlh(const float* __restrict__ ld,
                                             const float* __restrict__ h_all,
                                             f16* __restrict__ mlh) {
  int i = blockIdx.x * 256 + threadIdx.x;   // 12800*384
  int row = i / 384, h = i - row * 384;
  int b = row / 50, t = row - b * 50;
  float acc = 0.0f;
#pragma unroll
  for (int j = 0; j < 10; j++) {
    int s = t - 9 + j;
    if (s >= 0) acc += ld[row * 10 + j] * h_all[((long)s * 256 + b) * 384 + h];
  }
  mlh[i] = (f16)(acc * 0.1f);
}

// rnn_f16[b][t*384+h] = theme*conv + h
__global__ __launch_bounds__(256) void k_rnn(const float* __restrict__ theme,
                                             const float* __restrict__ conv,
                                             const float* __restrict__ h_all,
                                             f16* __restrict__ rnn) {
  int i = blockIdx.x * 256 + threadIdx.x;   // 12800*384, ordered (b,t,h)
  int row = i / 384, h = i - row * 384;
  int b = row / 50, t = row - b * 50;
  float local = theme[i] * conv[i];
  float hv = h_all[((long)t * 256 + b) * 384 + h];
  rnn[i] = (f16)(local + hv);               // (b*50+t)*384+h == b*19200 + t*384 + h
}

// out[i] = sum_z part[z][i] + out_b
__global__ __launch_bounds__(256) void k_red8(const float* __restrict__ part,
                                              const float* __restrict__ ob,
                                              float* __restrict__ out) {
  int i = blockIdx.x * 256 + threadIdx.x;   // 32768
  float s = 0.0f;
#pragma unroll
  for (int z = 0; z < 8; z++) s += part[z * 32768 + i];
  out[i] = s + ob[i & 127];
}

// ---------------- launch ----------------
extern "C" void kernel_launch(void* const* d_in, const int* in_sizes, int n_in,
                              void* d_out, int out_size, void* d_ws, size_t ws_size,
                              hipStream_t stream) {
  (void)in_sizes; (void)n_in; (void)out_size; (void)ws_size;
  const int*   node_ids  = (const int*)  d_in[0];
  const float* timep     = (const float*)d_in[3];
  const float* embed     = (const float*)d_in[6];
  const float* kernel_w  = (const float*)d_in[7];
  const float* kernel_b  = (const float*)d_in[8];
  const float* rec_w     = (const float*)d_in[9];
  const float* rec_b     = (const float*)d_in[10];
  const float* scale_w   = (const float*)d_in[11];
  const float* scale_b   = (const float*)d_in[12];
  const float* rescale_w = (const float*)d_in[13];
  const float* rescale_b = (const float*)d_in[14];
  const float* conv_w    = (const float*)d_in[15];
  const float* conv_b    = (const float*)d_in[16];
  const float* out_w     = (const float*)d_in[17];
  const float* out_b     = (const float*)d_in[18];

  char* ws = (char*)d_ws;
  f16*   xf      = (f16*)  (ws + OFF_X);
  f16*   lh      = (f16*)  (ws + OFF_LH);
  float* opart   = (float*)(ws + OFF_OPART);
  f16*   Wk      = (f16*)  (ws + OFF_WK);
  f16*   XKh     = (f16*)  (ws + OFF_XK);
  f16*   mlh_h   = (f16*)  (ws + OFF_MLH);
  f16*   s1h     = (f16*)  (ws + OFF_S1);
  float* theme   = (float*)(ws + OFF_TH);
  float* convbuf = (float*)(ws + OFF_CV);
  f16*   swp     = (f16*)  (ws + OFF_SWP);
  f16*   rwp2    = (f16*)  (ws + OFF_RWP2);
  float* sbp     = (float*)(ws + OFF_SBP);
  f16*   RW      = (f16*)  (ws + OFF_RW);
  float* biasc   = (float*)(ws + OFF_BIASC);
  float* h_all   = (float*)(ws + OFF_HALL);
  float* ldbuf   = (float*)(ws + OFF_LD);
  f16*   Wc2     = (f16*)  (ws + OFF_WC2);
  f16*   rnn     = (f16*)  (ws + OFF_RNN);
  f16*   outw    = (f16*)  (ws + OFF_OUTW);

  float* outp  = (float*)d_out;          // (256,128)
  float* dists = outp + 256 * 128;       // (50,256)

  // phase 0: prep
  k_gather    <<<25600, 256, 0, stream>>>(node_ids, embed, xf);
  k_prep_wk   <<<26624, 256, 0, stream>>>(kernel_w, kernel_b, rec_b, Wk, biasc);
  k_prep_rw   <<<2704,  256, 0, stream>>>(rec_w, kernel_w, RW);
  k_prep_scale<<<192,   256, 0, stream>>>(scale_w, scale_b, rescale_w, swp, sbp, rwp2);
  k_prep_wc   <<<5760,  256, 0, stream>>>(conv_w, Wc2);
  // phase 1: XKh = f16( x @ kernel_w^T + (kernel_b + rec_b) )
  k_gemm_bt<<<dim3(100, 13), 256, 0, stream>>>(xf, Wk, XKh, biasc, GP, 4096, 4096, 1);
  // phase 2: sequential recurrence (16 blocks -> RW L2-resident)
  k_recur<<<16, 512, 0, stream>>>(XKh, RW, timep, h_all, dists);
  // phase 3: deferred outputs (fully parallel)
  k_ld  <<<50,    256, 0, stream>>>(dists, ldbuf);
  k_lh  <<<24000, 256, 0, stream>>>(ldbuf, h_all, lh);
  k_mlh <<<19200, 256, 0, stream>>>(ldbuf, h_all, mlh_h);
  k_gemm_bt<<<dim3(100, 1), 256, 0, stream>>>(mlh_h, swp, s1h, sbp, 128, 384, 384, 2);
  k_gemm_bt<<<dim3(100, 3), 256, 0, stream>>>(s1h, rwp2, theme, rescale_b, 384, 128, 128, 3);
  k_gemm_bt<<<dim3(100, 3), 256, 0, stream>>>(lh, Wc2, convbuf, conv_b, 384, KH, KH, 0);
  k_rnn <<<19200, 256, 0, stream>>>(theme, convbuf, h_all, rnn);
  k_cvt <<<9600,  256, 0, stream>>>(out_w, outw, 128L * KO);
  // phase 4: out = rnn @ out_w^T + out_b   (K split 8 ways, then reduce)
  k_gemm_bt<<<dim3(2, 1, 8), 256, 0, stream>>>(rnn, outw, opart, nullptr, 128, KO, KO / 8, 0);
  k_red8<<<128, 256, 0, stream>>>(opart, out_b, outp);
}